// Round 3
// baseline (281.397 us; speedup 1.0000x reference)
//
#include <hip/hip_runtime.h>
#include <hip/hip_cooperative_groups.h>
#include <stdint.h>

namespace cg = cooperative_groups;

// Problem constants
#define NB   16      // batch
#define NC   128
#define NT   8
#define NBR  16
#define NS   8
#define NSY  64
#define NIN  16384   // = NC*NT*NBR = INPUT_SIZE

#define GRID 1024    // 4 blocks/CU co-resident (LDS 4x32KB=128<=160; VGPR<=128 via launch_bounds)

// ---------------------------------------------------------------------------
// One wave computes one branch's 16-batch output mask — pure VALU SWAR.
// lane = synapse (SY == 64). Per segment:
//   coalesced 256B idx load -> LDS gather of 16-bit batch mask ->
//   nibble-spread -> butterfly add (1,2,4) in nibbles -> bytes ->
//   butterfly add (8,16,32) -> per-byte >=16 threshold -> acc.
// Zero SALU in the hot loop (the round-2 ballot version was SALU/hazard-bound).
// ---------------------------------------------------------------------------
__device__ __forceinline__ uint32_t branch_mask_swar(const uint16_t* lds16,
                                                     const int* __restrict__ ip /* +lane */) {
    uint32_t acc0 = 0, acc1 = 0, acc2 = 0, acc3 = 0;
#pragma unroll 2
    for (int s = 0; s < NS; ++s) {
        const int iv = ip[s * NSY];
        uint32_t m = (uint32_t)lds16[iv & (NIN - 1)];
        m &= ~(uint32_t)(iv >> 31);                    // zero when iv == -1
        // spread bits -> nibble counters: x0 nibble j = batch j, x1 = batch j+8
        uint32_t x0 = m & 0xFFu, x1 = m >> 8;
        x0 = (x0 | (x0 << 12)) & 0x000F000Fu;
        x0 = (x0 | (x0 << 6))  & 0x03030303u;
        x0 = (x0 | (x0 << 3))  & 0x11111111u;
        x1 = (x1 | (x1 << 12)) & 0x000F000Fu;
        x1 = (x1 | (x1 << 6))  & 0x03030303u;
        x1 = (x1 | (x1 << 3))  & 0x11111111u;
        // butterfly levels 1,2,4 in nibbles (counts <= 8, fits)
        x0 += __shfl_xor(x0, 1);  x1 += __shfl_xor(x1, 1);
        x0 += __shfl_xor(x0, 2);  x1 += __shfl_xor(x1, 2);
        x0 += __shfl_xor(x0, 4);  x1 += __shfl_xor(x1, 4);
        // expand nibbles -> bytes: b0={0,2,4,6} b1={1,3,5,7} b2={8,10,12,14} b3={9,11,13,15}
        uint32_t b0 = x0 & 0x0F0F0F0Fu, b1 = (x0 >> 4) & 0x0F0F0F0Fu;
        uint32_t b2 = x1 & 0x0F0F0F0Fu, b3 = (x1 >> 4) & 0x0F0F0F0Fu;
        // butterfly levels 8,16,32 (counts <= 64, fits byte)
        b0 += __shfl_xor(b0, 8);   b1 += __shfl_xor(b1, 8);
        b2 += __shfl_xor(b2, 8);   b3 += __shfl_xor(b3, 8);
        b0 += __shfl_xor(b0, 16);  b1 += __shfl_xor(b1, 16);
        b2 += __shfl_xor(b2, 16);  b3 += __shfl_xor(b3, 16);
        b0 += __shfl_xor(b0, 32);  b1 += __shfl_xor(b1, 32);
        b2 += __shfl_xor(b2, 32);  b3 += __shfl_xor(b3, 32);
        // seg_on: byte >= 16  <=>  bit7 of (byte + 112)   (byte <= 64, no carry-out)
        acc0 += ((b0 + 0x70707070u) >> 7) & 0x01010101u;
        acc1 += ((b1 + 0x70707070u) >> 7) & 0x01010101u;
        acc2 += ((b2 + 0x70707070u) >> 7) & 0x01010101u;
        acc3 += ((b3 + 0x70707070u) >> 7) & 0x01010101u;
    }
    // branch_on: byte >= 4  <=>  bit3 of (byte + 4)   (acc <= 8, fits nibble)
    uint32_t on0 = ((acc0 + 0x04040404u) >> 3) & 0x01010101u;
    uint32_t on1 = ((acc1 + 0x04040404u) >> 3) & 0x01010101u;
    uint32_t on2 = ((acc2 + 0x04040404u) >> 3) & 0x01010101u;
    uint32_t on3 = ((acc3 + 0x04040404u) >> 3) & 0x01010101u;
    // recombine: nibble j = batch j, then compress nibbles -> bits
    uint32_t y0 = on0 | (on1 << 4);   // batches 0..7
    uint32_t y1 = on2 | (on3 << 4);   // batches 8..15
    y0 = (y0 | (y0 >> 3))  & 0x03030303u;
    y0 = (y0 | (y0 >> 6))  & 0x000F000Fu;
    y0 = (y0 | (y0 >> 12)) & 0xFFu;
    y1 = (y1 | (y1 >> 3))  & 0x03030303u;
    y1 = (y1 | (y1 >> 6))  & 0x000F000Fu;
    y1 = (y1 | (y1 >> 12)) & 0xFFu;
    return y0 | (y1 << 8);            // same value in all 64 lanes
}

// ---------------------------------------------------------------------------
// Fused: pack -> gridsync -> layer1 -> gridsync -> layer2. GRID x 256.
// ---------------------------------------------------------------------------
__global__ __launch_bounds__(256, 4) void k_fused(const float* __restrict__ x,
                                                  const int* __restrict__ idx1,
                                                  const int* __restrict__ idx2,
                                                  uint16_t* __restrict__ xpack,
                                                  uint16_t* __restrict__ act1pack,
                                                  int* __restrict__ out) {
    cg::grid_group grid = cg::this_grid();
    __shared__ __align__(16) uint16_t lds[NIN];   // 32 KB
    const int tid  = threadIdx.x;
    const int lane = tid & 63;
    const int wave = tid >> 6;
    const int bk   = blockIdx.x;                  // 0..GRID-1

    // ---- Phase 0: pack x into 16-bit batch masks. 16 positions per block. ----
    if (wave == 0) {
        const int pos = bk * 16 + (lane & 15);
        const int bg  = lane >> 4;                // 4 lane-groups x 4 batches
        uint32_t m = 0;
#pragma unroll
        for (int j = 0; j < 4; ++j) {
            const int b = bg * 4 + j;
            m |= (x[b * NIN + pos] != 0.0f) ? (1u << b) : 0u;
        }
        m |= __shfl_xor(m, 16);
        m |= __shfl_xor(m, 32);
        if (lane < 16) xpack[pos] = (uint16_t)m;
    }
    grid.sync();

    // ---- Phase 1: layer 1, 16 branches/block (4 per wave). ----
    {
        const uint4* s = (const uint4*)xpack;
        uint4* d = (uint4*)lds;
#pragma unroll
        for (int k = 0; k < 8; ++k)
            d[k * 256 + tid] = s[k * 256 + tid];
    }
    __syncthreads();

#pragma unroll
    for (int k = 0; k < 4; ++k) {
        const int bidx = bk * 16 + wave * 4 + k;          // [0, NIN)
        const int* ip = idx1 + bidx * (NS * NSY) + lane;
        const uint32_t om = branch_mask_swar(lds, ip);
        if (lane == 0) act1pack[bidx] = (uint16_t)om;
    }
    grid.sync();

    // ---- Phase 2: layer 2, t = 0 only. 2 branches/block (waves 0,1). ----
    {
        const uint4* s = (const uint4*)act1pack;
        uint4* d = (uint4*)lds;
#pragma unroll
        for (int k = 0; k < 8; ++k)
            d[k * 256 + tid] = s[k * 256 + tid];
    }
    __syncthreads();

    if (wave < 2) {
        const int j  = bk * 2 + wave;                     // [0, 2048)
        const int c  = j >> 4;
        const int br = j & 15;
        // branch (c, t=0, br): offset = ((c*NT + 0)*NBR + br) * NS*NSY
        const int* ip = idx2 + (c * (NT * NBR) + br) * (NS * NSY) + lane;
        const uint32_t om = branch_mask_swar(lds, ip);
        if (lane < NB) out[lane * (NC * NBR) + j] = (int)((om >> lane) & 1u);
    }
}

// ---------------------------------------------------------------------------
extern "C" void kernel_launch(void* const* d_in, const int* in_sizes, int n_in,
                              void* d_out, int out_size, void* d_ws, size_t ws_size,
                              hipStream_t stream) {
    const float* x    = (const float*)d_in[0];
    const int*   idx1 = (const int*)d_in[1];
    const int*   idx2 = (const int*)d_in[2];

    uint16_t* xpack    = (uint16_t*)d_ws;                       // 32 KB
    uint16_t* act1pack = (uint16_t*)((char*)d_ws + 32768);      // 32 KB
    int*      out      = (int*)d_out;

    void* args[] = {(void*)&x, (void*)&idx1, (void*)&idx2,
                    (void*)&xpack, (void*)&act1pack, (void*)&out};
    hipLaunchCooperativeKernel((const void*)k_fused, dim3(GRID), dim3(256),
                               args, 0, stream);
}

// Round 4
// 105.144 us; speedup vs baseline: 2.6763x; 2.6763x over previous
//
#include <hip/hip_runtime.h>
#include <stdint.h>

// Problem constants
#define NB   16      // batch
#define NC   128
#define NT   8
#define NBR  16
#define NS   8
#define NSY  64
#define NIN  16384   // = NC*NT*NBR = INPUT_SIZE

// ---------------------------------------------------------------------------
// Kernel A: pack x (B x NIN float 0/1) into per-position 16-bit batch masks.
// ---------------------------------------------------------------------------
__global__ __launch_bounds__(256) void k_pack(const float* __restrict__ x,
                                              uint16_t* __restrict__ xpack) {
    const int i = blockIdx.x * 256 + threadIdx.x;   // grid = 64*256 = NIN
    uint32_t m = 0;
#pragma unroll
    for (int b = 0; b < NB; ++b)
        m |= (x[b * NIN + i] != 0.0f) ? (1u << b) : 0u;
    xpack[i] = (uint16_t)m;
}

// ---------------------------------------------------------------------------
__device__ __forceinline__ void stage(const uint16_t* __restrict__ g,
                                      uint16_t* l, int tid) {
    const uint4* s = (const uint4*)g;
    uint4* d = (uint4*)l;
#pragma unroll
    for (int k = 0; k < 8; ++k) d[k * 256 + tid] = s[k * 256 + tid];
}

// ---------------------------------------------------------------------------
// Transpose-popcount: one wave computes TWO branches' 16-batch masks.
// Per segment: gather (1 ds_read_u16) -> write 64 masks to per-wave scratch
// (ds_write_b16, 2-way=free) -> each lane reads its quarter's 16 masks
// (2 x ds_read_b128, 4 distinct addrs + broadcast, conflict-free) ->
// per-lane popcount of batch bit (8x v_and + v_bcnt) -> 2 shuffles to sum
// quarters. Replaces the 12-swizzle butterfly (round-3: latency-serial) and
// the 16-ballot SALU chain (round-2).
// ---------------------------------------------------------------------------
__device__ __forceinline__ void pair_masks(const uint16_t* __restrict__ lds16,
                                           uint16_t* __restrict__ s0,
                                           uint16_t* __restrict__ s1,
                                           const int* __restrict__ ip0,
                                           const int* __restrict__ ip1,
                                           int lane, uint32_t sel,
                                           uint32_t& om0, uint32_t& om1) {
    int iv0[NS], iv1[NS];
#pragma unroll
    for (int s = 0; s < NS; ++s) { iv0[s] = ip0[s * NSY]; iv1[s] = ip1[s * NSY]; }
    const uint4* r0 = (const uint4*)(s0 + ((lane >> 4) << 4));
    const uint4* r1 = (const uint4*)(s1 + ((lane >> 4) << 4));
    int bs0 = 0, bs1 = 0;
#pragma unroll
    for (int s = 0; s < NS; ++s) {
        const uint32_t m0 = (uint32_t)lds16[iv0[s] & (NIN - 1)] & ~(uint32_t)(iv0[s] >> 31);
        const uint32_t m1 = (uint32_t)lds16[iv1[s] & (NIN - 1)] & ~(uint32_t)(iv1[s] >> 31);
        __builtin_amdgcn_wave_barrier();   // keep prior reads before these writes
        s0[lane] = (uint16_t)m0;
        s1[lane] = (uint16_t)m1;
        __builtin_amdgcn_wave_barrier();   // keep writes before reads (HW: same-wave DS in order)
        const uint4 a0 = r0[0], c0 = r0[1];
        const uint4 a1 = r1[0], c1 = r1[1];
        __builtin_amdgcn_wave_barrier();
        int cnt0 = __popc(a0.x & sel) + __popc(a0.y & sel) + __popc(a0.z & sel) + __popc(a0.w & sel)
                 + __popc(c0.x & sel) + __popc(c0.y & sel) + __popc(c0.z & sel) + __popc(c0.w & sel);
        int cnt1 = __popc(a1.x & sel) + __popc(a1.y & sel) + __popc(a1.z & sel) + __popc(a1.w & sel)
                 + __popc(c1.x & sel) + __popc(c1.y & sel) + __popc(c1.z & sel) + __popc(c1.w & sel);
        cnt0 += __shfl_xor(cnt0, 16);  cnt0 += __shfl_xor(cnt0, 32);
        cnt1 += __shfl_xor(cnt1, 16);  cnt1 += __shfl_xor(cnt1, 32);
        bs0 += (cnt0 >= 16) ? 1 : 0;          // SEG_TH
        bs1 += (cnt1 >= 16) ? 1 : 0;
    }
    om0 = (uint32_t)(__ballot(bs0 >= 4) & 0xFFFFull);   // BR_TH; lanes L,L+16.. agree
    om1 = (uint32_t)(__ballot(bs1 >= 4) & 0xFFFFull);
}

// ---------------------------------------------------------------------------
// Layer 1: 1024 blocks x 256. 16 branches/block (2 per wave x 2 iters).
// ---------------------------------------------------------------------------
__global__ __launch_bounds__(256) void k_layer1(const uint16_t* __restrict__ xpack,
                                                const int* __restrict__ idx1,
                                                uint16_t* __restrict__ act1pack) {
    __shared__ __align__(16) uint16_t lds[NIN];        // 32 KB
    __shared__ __align__(16) uint16_t scr[4 * 2 * 64]; // 1 KB per-wave scratch
    const int tid = threadIdx.x, lane = tid & 63, wave = tid >> 6;
    stage(xpack, lds, tid);
    __syncthreads();
    const uint32_t sel = 0x00010001u << (lane & 15);
    uint16_t* s0 = scr + (wave * 2 + 0) * 64;
    uint16_t* s1 = scr + (wave * 2 + 1) * 64;
#pragma unroll
    for (int it = 0; it < 2; ++it) {
        const int b0 = blockIdx.x * 16 + wave * 4 + it * 2;
        const int b1 = b0 + 1;
        uint32_t om0, om1;
        pair_masks(lds, s0, s1,
                   idx1 + b0 * (NS * NSY) + lane,
                   idx1 + b1 * (NS * NSY) + lane,
                   lane, sel, om0, om1);
        if (lane == 0) { act1pack[b0] = (uint16_t)om0; act1pack[b1] = (uint16_t)om1; }
    }
}

// ---------------------------------------------------------------------------
// Layer 2: t = 0 only, 2048 branches. 256 blocks x 256. 8 branches/block.
// ---------------------------------------------------------------------------
__global__ __launch_bounds__(256) void k_layer2(const uint16_t* __restrict__ act1pack,
                                                const int* __restrict__ idx2,
                                                int* __restrict__ out) {
    __shared__ __align__(16) uint16_t lds[NIN];
    __shared__ __align__(16) uint16_t scr[4 * 2 * 64];
    const int tid = threadIdx.x, lane = tid & 63, wave = tid >> 6;
    stage(act1pack, lds, tid);
    __syncthreads();
    const uint32_t sel = 0x00010001u << (lane & 15);
    uint16_t* s0 = scr + (wave * 2 + 0) * 64;
    uint16_t* s1 = scr + (wave * 2 + 1) * 64;
    const int j0 = blockIdx.x * 8 + wave * 2;          // [0, 2048)
    const int j1 = j0 + 1;
    const int c0 = j0 >> 4, br0 = j0 & 15;
    const int c1 = j1 >> 4, br1 = j1 & 15;
    uint32_t om0, om1;
    pair_masks(lds, s0, s1,
               idx2 + (c0 * (NT * NBR) + br0) * (NS * NSY) + lane,
               idx2 + (c1 * (NT * NBR) + br1) * (NS * NSY) + lane,
               lane, sel, om0, om1);
    if (lane < NB) {
        out[lane * (NC * NBR) + j0] = (int)((om0 >> lane) & 1u);
        out[lane * (NC * NBR) + j1] = (int)((om1 >> lane) & 1u);
    }
}

// ---------------------------------------------------------------------------
extern "C" void kernel_launch(void* const* d_in, const int* in_sizes, int n_in,
                              void* d_out, int out_size, void* d_ws, size_t ws_size,
                              hipStream_t stream) {
    const float* x    = (const float*)d_in[0];
    const int*   idx1 = (const int*)d_in[1];
    const int*   idx2 = (const int*)d_in[2];

    uint16_t* xpack    = (uint16_t*)d_ws;                       // 32 KB
    uint16_t* act1pack = (uint16_t*)((char*)d_ws + 32768);      // 32 KB
    int*      out      = (int*)d_out;

    k_pack  <<<NIN / 256, 256, 0, stream>>>(x, xpack);
    k_layer1<<<NIN / 16,  256, 0, stream>>>(xpack, idx1, act1pack);
    k_layer2<<<(NC * NBR) / 8, 256, 0, stream>>>(act1pack, idx2, out);
}